// Round 1
// 1095.801 us; speedup vs baseline: 1.0110x; 1.0110x over previous
//
#include <hip/hip_runtime.h>
#include <math.h>

// Problem constants
#define LAYERS 6
#define DMODEL 512
#define NHEAD 8
#define DHEAD 64
#define FFDIM 2048
#define BATCH 8
#define SEQ 1024
#define ROWS (BATCH * SEQ)   // 8192
#define EPS 1e-5f

typedef __attribute__((ext_vector_type(8))) short bf16x8;
typedef __attribute__((ext_vector_type(4))) float f32x4;

__device__ inline short f2bf(float f) {
    union { float f; unsigned u; } v; v.f = f;
    unsigned r = (v.u + 0x7FFFu + ((v.u >> 16) & 1u)) >> 16;
    return (short)r;
}

// async global(bf16,16B) -> LDS staging; data lands at wave-uniform base + lane*16
#define GLOAD_LDS16(g, l)                                                      \
    __builtin_amdgcn_global_load_lds(                                          \
        (__attribute__((address_space(1))) void*)(g),                          \
        (__attribute__((address_space(3))) void*)(l), 16, 0, 0)

// ---------------------------------------------------------------------------
// Weight transpose + fp32->bf16: src [L][K][N] f32 -> dst [L][N][K] bf16
// ---------------------------------------------------------------------------
__global__ void wtrans_kernel(const float* __restrict__ src, short* __restrict__ dst,
                              int K, int N) {
    __shared__ float t[32][33];
    const size_t mofs = (size_t)blockIdx.z * K * N;
    src += mofs; dst += mofs;
    int n0 = blockIdx.x * 32, k0 = blockIdx.y * 32;
    int tx = threadIdx.x, ty = threadIdx.y;
#pragma unroll
    for (int i = 0; i < 4; ++i)
        t[ty + 8 * i][tx] = src[(size_t)(k0 + ty + 8 * i) * N + n0 + tx];
    __syncthreads();
#pragma unroll
    for (int i = 0; i < 4; ++i)
        dst[(size_t)(n0 + ty + 8 * i) * K + k0 + tx] = f2bf(t[tx][ty + 8 * i]);
}

// ---------------------------------------------------------------------------
// Positional scan
// ---------------------------------------------------------------------------
__global__ void pos_scan_kernel(const int* __restrict__ mask, int* __restrict__ pos) {
    __shared__ int sm[SEQ];
    int b = blockIdx.x;
    int t = threadIdx.x;
    int v = (mask[b * SEQ + t] != 0) ? 1 : 0;
    sm[t] = v;
    __syncthreads();
    for (int off = 1; off < SEQ; off <<= 1) {
        int add = (t >= off) ? sm[t - off] : 0;
        __syncthreads();
        sm[t] += add;
        __syncthreads();
    }
    pos[b * SEQ + t] = sm[t] * v;
}

// ---------------------------------------------------------------------------
// x = x_in + sin_pos_table[pos]; writes fp32 master + bf16 copy
// ---------------------------------------------------------------------------
__global__ void add_pos_kernel(const float* __restrict__ xin, const int* __restrict__ pos,
                               float* __restrict__ xout, short* __restrict__ xb) {
    int bs = blockIdx.x;
    int t = threadIdx.x;
    int p = pos[bs];
    int d0 = t * 4;
    const float C = -logf(10000.0f) * (1.0f / 255.0f);  // half-1 = 255
    float4 xv = *(const float4*)(xin + (size_t)bs * DMODEL + d0);
    float e[4];
#pragma unroll
    for (int j = 0; j < 4; ++j) {
        int d = d0 + j;
        if (p == 0) {
            e[j] = 0.0f;
        } else {
            int dd = (d < 256) ? d : d - 256;
            float freq = expf((float)dd * C);
            float ang = (float)p * freq;
            e[j] = (d < 256) ? sinf(ang) : cosf(ang);
        }
    }
    float4 ov;
    ov.x = xv.x + e[0]; ov.y = xv.y + e[1]; ov.z = xv.z + e[2]; ov.w = xv.w + e[3];
    *(float4*)(xout + (size_t)bs * DMODEL + d0) = ov;
    short4 sb;
    sb.x = f2bf(ov.x); sb.y = f2bf(ov.y); sb.z = f2bf(ov.z); sb.w = f2bf(ov.w);
    *(short4*)(xb + (size_t)bs * DMODEL + d0) = sb;
}

// ===========================================================================
// LDS k-granule swizzle (both GEMM kernels):
//   store: staging lane (r=lane>>2, pos=lane&3) fetches global granule
//          g' = (pos - (r>>1)) & 3  -> granule q of row m lands at LDS
//          position (q + ((m&15)>>1)) & 3.
//   read:  fragment (m, quad) at granule position (quad + (lr>>1)) & 3
//          (since m&15 == lr for all fragment rows).
//   Result: read bank-group (lr&1)*4 + (quad+(lr>>1))&3 covers all 8 groups
//   2-way across 16 lanes -> conflict-free (was 8-way).
// ===========================================================================

// ---------------------------------------------------------------------------
// bf16 MFMA GEMM, 128x128 tile, BK=32, 256 thr, single-barrier double-buffer.
// C[M,N] = A[M,K] @ BT[N,K]^T (+bias)(+relu).
// ---------------------------------------------------------------------------
template <bool OUTBF16, bool BIAS, bool RELU>
__global__ __launch_bounds__(256) void gemm_bf16_kernel(const short* __restrict__ A,
                                                        const short* __restrict__ BT,
                                                        const float* __restrict__ bias,
                                                        void* __restrict__ Cv,
                                                        int M, int N, int K) {
    __shared__ __attribute__((aligned(16))) short Asm[2][128 * 32];
    __shared__ __attribute__((aligned(16))) short Bsm[2][128 * 32];
    const int tid = threadIdx.x;
    const int w = tid >> 6;
    const int lane = tid & 63;
    const int quad = lane >> 4;
    const int lr = lane & 15;
    const int m0 = blockIdx.y * 128;
    const int n0 = blockIdx.x * 128;
    const int wm = (w >> 1) * 64;
    const int wn = (w & 1) * 64;

    // staging: 8 segments of 16 rows; wave w owns segs {2w, 2w+1}
    const int segr = lane >> 2;
    const int segk = (((lane & 3) - (lane >> 3)) & 3) * 8;  // swizzled source granule
    const int sA0 = w * 2, sA1 = w * 2 + 1;
    const short* gA0 = A + (size_t)(m0 + sA0 * 16 + segr) * K + segk;
    const short* gA1 = A + (size_t)(m0 + sA1 * 16 + segr) * K + segk;
    const short* gB0 = BT + (size_t)(n0 + sA0 * 16 + segr) * K + segk;
    const short* gB1 = BT + (size_t)(n0 + sA1 * 16 + segr) * K + segk;
    const int lofs0 = sA0 * 512 + lane * 8;
    const int lofs1 = sA1 * 512 + lane * 8;
    const int gp = ((quad + (lr >> 1)) & 3) * 8;            // swizzled read position

    f32x4 acc[4][4];
#pragma unroll
    for (int i = 0; i < 4; ++i)
#pragma unroll
        for (int j = 0; j < 4; ++j) { acc[i][j][0] = 0.f; acc[i][j][1] = 0.f; acc[i][j][2] = 0.f; acc[i][j][3] = 0.f; }

    GLOAD_LDS16(gA0, &Asm[0][lofs0]);
    GLOAD_LDS16(gA1, &Asm[0][lofs1]);
    GLOAD_LDS16(gB0, &Bsm[0][lofs0]);
    GLOAD_LDS16(gB1, &Bsm[0][lofs1]);

    const int nk = K >> 5;
    for (int i = 0; i < nk; ++i) {
        __syncthreads();
        if (i + 1 < nk) {
            const int k1 = (i + 1) * 32;
            const int nb = (i + 1) & 1;
            GLOAD_LDS16(gA0 + k1, &Asm[nb][lofs0]);
            GLOAD_LDS16(gA1 + k1, &Asm[nb][lofs1]);
            GLOAD_LDS16(gB0 + k1, &Bsm[nb][lofs0]);
            GLOAD_LDS16(gB1 + k1, &Bsm[nb][lofs1]);
        }
        const int cur = i & 1;
        bf16x8 af[4], bfr[4];
#pragma unroll
        for (int mt = 0; mt < 4; ++mt)
            af[mt] = *(const bf16x8*)&Asm[cur][(wm + mt * 16 + lr) * 32 + gp];
#pragma unroll
        for (int nt = 0; nt < 4; ++nt)
            bfr[nt] = *(const bf16x8*)&Bsm[cur][(wn + nt * 16 + lr) * 32 + gp];
#pragma unroll
        for (int mt = 0; mt < 4; ++mt)
#pragma unroll
            for (int nt = 0; nt < 4; ++nt)
                acc[mt][nt] = __builtin_amdgcn_mfma_f32_16x16x32_bf16(af[mt], bfr[nt], acc[mt][nt], 0, 0, 0);
    }

    float bv[4];
    if (BIAS) {
#pragma unroll
        for (int nt = 0; nt < 4; ++nt) bv[nt] = bias[n0 + wn + nt * 16 + lr];
    }
#pragma unroll
    for (int mt = 0; mt < 4; ++mt)
#pragma unroll
        for (int nt = 0; nt < 4; ++nt)
#pragma unroll
            for (int r = 0; r < 4; ++r) {
                float v = acc[mt][nt][r];
                if (BIAS) v += bv[nt];
                if (RELU) v = fmaxf(v, 0.f);
                int row = m0 + wm + mt * 16 + quad * 4 + r;
                int col = n0 + wn + nt * 16 + lr;
                if (OUTBF16)
                    ((short*)Cv)[(size_t)row * N + col] = f2bf(v);
                else
                    ((float*)Cv)[(size_t)row * N + col] = v;
            }
}

// ---------------------------------------------------------------------------
// bf16 MFMA GEMM, 64x128 tile (for N=512 GEMMs: 512 blocks = 2/CU, A streamed
// exactly once, B fits per-XCD L2). BK=32, 256 thr = 4 waves (2x2 of 32x64).
// ---------------------------------------------------------------------------
template <bool OUTBF16, bool BIAS, bool RELU>
__global__ __launch_bounds__(256) void gemm_bf16_m64_kernel(const short* __restrict__ A,
                                                            const short* __restrict__ BT,
                                                            const float* __restrict__ bias,
                                                            void* __restrict__ Cv,
                                                            int M, int N, int K) {
    __shared__ __attribute__((aligned(16))) short Asm[2][64 * 32];
    __shared__ __attribute__((aligned(16))) short Bsm[2][128 * 32];
    const int tid = threadIdx.x;
    const int w = tid >> 6;
    const int lane = tid & 63;
    const int quad = lane >> 4;
    const int lr = lane & 15;
    const int m0 = blockIdx.y * 64;
    const int n0 = blockIdx.x * 128;
    const int wm = (w >> 1) * 32;
    const int wn = (w & 1) * 64;

    // staging: A = 4 segs (wave w -> seg w), B = 8 segs (wave w -> 2w, 2w+1)
    const int segr = lane >> 2;
    const int segk = (((lane & 3) - (lane >> 3)) & 3) * 8;  // swizzled source granule
    const short* gA  = A + (size_t)(m0 + w * 16 + segr) * K + segk;
    const short* gB0 = BT + (size_t)(n0 + (2 * w) * 16 + segr) * K + segk;
    const short* gB1 = BT + (size_t)(n0 + (2 * w + 1) * 16 + segr) * K + segk;
    const int lA  = w * 512 + lane * 8;
    const int lB0 = (2 * w) * 512 + lane * 8;
    const int lB1 = (2 * w + 1) * 512 + lane * 8;
    const int gp = ((quad + (lr >> 1)) & 3) * 8;            // swizzled read position

    f32x4 acc[2][4];
#pragma unroll
    for (int i = 0; i < 2; ++i)
#pragma unroll
        for (int j = 0; j < 4; ++j) { acc[i][j][0] = 0.f; acc[i][j][1] = 0.f; acc[i][j][2] = 0.f; acc[i][j][3] = 0.f; }

    GLOAD_LDS16(gA, &Asm[0][lA]);
    GLOAD_LDS16(gB0, &Bsm[0][lB0]);
    GLOAD_LDS16(gB1, &Bsm[0][lB1]);

    const int nk = K >> 5;
    for (int i = 0; i < nk; ++i) {
        __syncthreads();
        if (i + 1 < nk) {
            const int k1 = (i + 1) * 32;
            const int nb = (i + 1) & 1;
            GLOAD_LDS16(gA + k1, &Asm[nb][lA]);
            GLOAD_LDS16(gB0 + k1, &Bsm[nb][lB0]);
            GLOAD_LDS16(gB1 + k1, &Bsm[nb][lB1]);
        }
        const int cur = i & 1;
        bf16x8 af[2], bfr[4];
#pragma unroll
        for (int mt = 0; mt < 2; ++mt)
            af[mt] = *(const bf16x8*)&Asm[cur][(wm + mt * 16 + lr) * 32 + gp];
#pragma unroll
        for (int nt = 0; nt < 4; ++nt)
            bfr[nt] = *(const bf16x8*)&Bsm[cur][(wn + nt * 16 + lr) * 32 + gp];
#pragma unroll
        for (int mt = 0; mt < 2; ++mt)
#pragma unroll
            for (int nt = 0; nt < 4; ++nt)
                acc[mt][nt] = __builtin_amdgcn_mfma_f32_16x16x32_bf16(af[mt], bfr[nt], acc[mt][nt], 0, 0, 0);
    }

    float bv[4];
    if (BIAS) {
#pragma unroll
        for (int nt = 0; nt < 4; ++nt) bv[nt] = bias[n0 + wn + nt * 16 + lr];
    }
#pragma unroll
    for (int mt = 0; mt < 2; ++mt)
#pragma unroll
        for (int nt = 0; nt < 4; ++nt)
#pragma unroll
            for (int r = 0; r < 4; ++r) {
                float v = acc[mt][nt][r];
                if (BIAS) v += bv[nt];
                if (RELU) v = fmaxf(v, 0.f);
                int row = m0 + wm + mt * 16 + quad * 4 + r;
                int col = n0 + wn + nt * 16 + lr;
                if (OUTBF16)
                    ((short*)Cv)[(size_t)row * N + col] = f2bf(v);
                else
                    ((float*)Cv)[(size_t)row * N + col] = v;
            }
}

// ---------------------------------------------------------------------------
// bf16-MFMA flash attention v3: QTILE=128 (512 thr = 8 waves, 16 q-rows each)
// -> 512 blocks = 2 blocks/CU so barrier/staging stalls of one block hide
// under the other. QK^T computed SWAPPED (S^T = mfma(K,Q)) so each lane holds
// P^T[key=16t+4*quad+r][q=lr]: the 4 P-values per lane are k-contiguous ->
// P store is 4x ds_write_b64 of cvt_pk-packed bf16 (was 32x ds_write_b16 with
// 4-way bank conflicts). Row-sum becomes per-lane scalar, reduced across
// quads once at the end. No-rescale softmax (fixed shift 8, exact after
// normalization), double-buffered K/V staging, ONE barrier per tile.
// ---------------------------------------------------------------------------
#define QTILE 128
__global__ __launch_bounds__(512, 4) void attn_mfma_kernel(const short* __restrict__ qkv,
                                                           const int* __restrict__ mask,
                                                           short* __restrict__ o) {
    __shared__ __attribute__((aligned(16))) short Ks[2][64][72];    // [key][d]
    __shared__ __attribute__((aligned(16))) short Vt[2][64][72];    // [d][key]
    __shared__ __attribute__((aligned(16))) short Ps[8][16][72];    // per-wave P[q][key]
    __shared__ float Msf[2][64];

    const int qt = blockIdx.x;          // 0..7
    const int bh = blockIdx.y;          // 0..63
    const int b = bh >> 3, h = bh & 7;
    const int tid = threadIdx.x;
    const int w = tid >> 6;             // wave 0..7
    const int lane = tid & 63;
    const int quad = lane >> 4;
    const int lr = lane & 15;
    const size_t seqrow = (size_t)b * SEQ;

    // Q fragment: 16 q-rows per wave, q = qt*128 + w*16 + lr
    bf16x8 qf[2];
#pragma unroll
    for (int c = 0; c < 2; ++c)
        qf[c] = *(const bf16x8*)(qkv +
            (seqrow + qt * QTILE + w * 16 + lr) * (3 * DMODEL)
            + h * DHEAD + c * 32 + quad * 8);

    const bool isK = (tid < 256);
    const int st = isK ? tid : tid - 256;
    const int kkey = st >> 2;
    const int kg = (st & 3) * 8;
    const int vkp = st & 31;
    const int vdg = st >> 5;
    const short* gK = qkv + (seqrow + kkey) * (3 * DMODEL) + DMODEL + h * DHEAD + kg;
    const short* gV = qkv + (seqrow + 2 * vkp) * (3 * DMODEL) + 2 * DMODEL + h * DHEAD + vdg * 8;

    bf16x8 r0, r1;
    int mreg = 0;

    {
        if (isK) {
            r0 = *(const bf16x8*)(gK);
            r1 = *(const bf16x8*)(gK + 32);
        } else {
            r0 = *(const bf16x8*)(gV);
            r1 = *(const bf16x8*)(gV + 3 * DMODEL);
        }
        if (tid < 64) mreg = mask[seqrow + tid];
        if (isK) {
            *(bf16x8*)&Ks[0][kkey][kg] = r0;
            *(bf16x8*)&Ks[0][kkey][kg + 32] = r1;
        } else {
#pragma unroll
            for (int i = 0; i < 8; ++i) {
                short2 p; p.x = r0[i]; p.y = r1[i];
                *(short2*)&Vt[0][vdg * 8 + i][vkp * 2] = p;
            }
        }
        if (tid < 64) Msf[0][tid] = mreg ? 1.0f : 0.0f;
    }
    __syncthreads();

    f32x4 Oacc[4];
    float rs = 0.f;
#pragma unroll
    for (int t2 = 0; t2 < 4; ++t2) { Oacc[t2][0] = 0.f; Oacc[t2][1] = 0.f; Oacc[t2][2] = 0.f; Oacc[t2][3] = 0.f; }

    for (int kt = 0; kt < 16; ++kt) {
        const int cur = kt & 1;
        {
            const size_t ofs = (size_t)((kt + 1) & 15) * 64 * (3 * DMODEL);
            if (isK) {
                r0 = *(const bf16x8*)(gK + ofs);
                r1 = *(const bf16x8*)(gK + ofs + 32);
            } else {
                r0 = *(const bf16x8*)(gV + ofs);
                r1 = *(const bf16x8*)(gV + ofs + 3 * DMODEL);
            }
            if (tid < 64) mreg = mask[seqrow + ((kt + 1) & 15) * 64 + tid];
        }
        bf16x8 kf[2][4], vf[2][4];
#pragma unroll
        for (int c = 0; c < 2; ++c)
#pragma unroll
            for (int t = 0; t < 4; ++t) {
                kf[c][t] = *(const bf16x8*)&Ks[cur][lr + 16 * t][quad * 8 + 32 * c];
                vf[c][t] = *(const bf16x8*)&Vt[cur][lr + 16 * t][quad * 8 + 32 * c];
            }

        // S^T[key][q]: A = K rows (key=16t+quad*4+r), B = Q^T (col q=lr)
        f32x4 S[4];
#pragma unroll
        for (int t = 0; t < 4; ++t) { S[t][0] = 0.f; S[t][1] = 0.f; S[t][2] = 0.f; S[t][3] = 0.f; }
#pragma unroll
        for (int c = 0; c < 2; ++c)
#pragma unroll
            for (int t = 0; t < 4; ++t)
                S[t] = __builtin_amdgcn_mfma_f32_16x16x32_bf16(kf[c][t], qf[c], S[t], 0, 0, 0);

#pragma unroll
        for (int t = 0; t < 4; ++t) {
            f32x4 mvv = *(const f32x4*)&Msf[cur][16 * t + 4 * quad];  // mask on key, broadcast
            float p0 = __expf(S[t][0] - 8.0f) * mvv[0];
            float p1 = __expf(S[t][1] - 8.0f) * mvv[1];
            float p2 = __expf(S[t][2] - 8.0f) * mvv[2];
            float p3 = __expf(S[t][3] - 8.0f) * mvv[3];
            rs += (p0 + p1) + (p2 + p3);
            unsigned lo, hi;
            asm("v_cvt_pk_bf16_f32 %0, %1, %2" : "=v"(lo) : "v"(p0), "v"(p1));
            asm("v_cvt_pk_bf16_f32 %0, %1, %2" : "=v"(hi) : "v"(p2), "v"(p3));
            // P^T values are k-contiguous: Ps[q=lr][k = 16t+4*quad .. +3]
            uint2 pk; pk.x = lo; pk.y = hi;
            *(uint2*)&Ps[w][lr][16 * t + 4 * quad] = pk;
        }
        // same-wave LDS RAW (all quads wrote row lr's segments); compiler
        // orders via lgkmcnt, no barrier needed (Ps[w] is wave-private).
        bf16x8 pa0 = *(const bf16x8*)&Ps[w][lr][quad * 8];
        bf16x8 pa1 = *(const bf16x8*)&Ps[w][lr][quad * 8 + 32];
#pragma unroll
        for (int t2 = 0; t2 < 4; ++t2) {
            Oacc[t2] = __builtin_amdgcn_mfma_f32_16x16x32_bf16(pa0, vf[0][t2], Oacc[t2], 0, 0, 0);
            Oacc[t2] = __builtin_amdgcn_mfma_f32_16x16x32_bf16(pa1, vf[1][t2], Oacc[t2], 0, 0, 0);
        }

        {
            const int nb = cur ^ 1;
            if (isK) {
                *(bf16x8*)&Ks[nb][kkey][kg] = r0;
                *(bf16x8*)&Ks[nb][kkey][kg + 32] = r1;
            } else {
#pragma unroll
                for (int i = 0; i < 8; ++i) {
                    short2 p; p.x = r0[i]; p.y = r1[i];
                    *(short2*)&Vt[nb][vdg * 8 + i][vkp * 2] = p;
                }
            }
            if (tid < 64) Msf[nb][tid] = mreg ? 1.0f : 0.0f;
        }
        __syncthreads();
    }

    // rs holds partial sum for q=lr (keys {16t+4*quad+r}); reduce across quads
    rs += __shfl_xor(rs, 16);
    rs += __shfl_xor(rs, 32);          // now every lane: full sum for q = its lr
    float inv[4];
#pragma unroll
    for (int r = 0; r < 4; ++r)
        inv[r] = 1.f / __shfl(rs, quad * 4 + r);   // sum for q-row quad*4+r

#pragma unroll
    for (int t2 = 0; t2 < 4; ++t2)
#pragma unroll
        for (int r = 0; r < 4; ++r) {
            int row = qt * QTILE + w * 16 + quad * 4 + r;
            o[(seqrow + row) * DMODEL + h * DHEAD + 16 * t2 + lr] = f2bf(Oacc[t2][r] * inv[r]);
        }
}

// ---------------------------------------------------------------------------
// x = LayerNorm(tmp + x) * g + b; writes fp32 master (in-place) + bf16 copy
// ---------------------------------------------------------------------------
__global__ __launch_bounds__(64) void ln_kernel(const float* __restrict__ tmp,
                                                float* __restrict__ x,
                                                short* __restrict__ xb,
                                                const float* __restrict__ g,
                                                const float* __restrict__ bta) {
    const int row = blockIdx.x;
    const int t = threadIdx.x;
    const size_t base = (size_t)row * DMODEL + t * 8;
    float4 x0 = *(const float4*)(x + base);
    float4 x1 = *(const float4*)(x + base + 4);
    float4 t0 = *(const float4*)(tmp + base);
    float4 t1 = *(const float4*)(tmp + base + 4);
    float v[8];
    v[0] = x0.x + t0.x; v[1] = x0.y + t0.y; v[2] = x0.z + t0.z; v[3] = x0.w + t0.w;
    v[4] = x1.x + t1.x; v[5] = x1.y + t1.y; v[6] = x1.z + t1.z; v[7] = x1.w + t1.w;
    float s = 0.f, sq = 0.f;
#pragma unroll
    for (int i = 0; i < 8; ++i) { s += v[i]; sq += v[i] * v[i]; }
#pragma unroll
    for (int off = 1; off < 64; off <<= 1) {
        s += __shfl_xor(s, off);
        sq += __shfl_xor(sq, off);
    }
    float mu = s * (1.0f / DMODEL);
    float var = sq * (1.0f / DMODEL) - mu * mu;
    float r = rsqrtf(var + EPS);
    float4 g0 = *(const float4*)(g + t * 8);
    float4 g1 = *(const float4*)(g + t * 8 + 4);
    float4 b0 = *(const float4*)(bta + t * 8);
    float4 b1 = *(const float4*)(bta + t * 8 + 4);
    float ov[8];
    ov[0] = (v[0] - mu) * r * g0.x + b0.x;
    ov[1] = (v[1] - mu) * r * g0.y + b0.y;
    ov[2] = (v[2] - mu) * r * g0.z + b0.z;
    ov[3] = (v[3] - mu) * r * g0.w + b0.w;
    ov[4] = (v[4] - mu) * r * g1.x + b1.x;
    ov[5] = (v[5] - mu) * r * g1.y + b1.y;
    ov[6] = (v[6] - mu) * r * g1.z + b1.z;
    ov[7] = (v[7] - mu) * r * g1.w + b1.w;
    *(float4*)(x + base) = *(float4*)&ov[0];
    *(float4*)(x + base + 4) = *(float4*)&ov[4];
    bf16x8 ob;
#pragma unroll
    for (int i = 0; i < 8; ++i) ob[i] = f2bf(ov[i]);
    *(bf16x8*)(xb + base) = ob;
}

// ---------------------------------------------------------------------------
extern "C" void kernel_launch(void* const* d_in, const int* in_sizes, int n_in,
                              void* d_out, int out_size, void* d_ws, size_t ws_size,
                              hipStream_t stream) {
    const float* x_in  = (const float*)d_in[0];
    const int*   mask  = (const int*)d_in[3];
    const float* Wqkv  = (const float*)d_in[4];
    const float* Wfc   = (const float*)d_in[5];
    const float* bfc   = (const float*)d_in[6];
    const float* ln1_g = (const float*)d_in[7];
    const float* ln1_b = (const float*)d_in[8];
    const float* ln2_g = (const float*)d_in[9];
    const float* ln2_b = (const float*)d_in[10];
    const float* W1    = (const float*)d_in[11];
    const float* b1    = (const float*)d_in[12];
    const float* W2    = (const float*)d_in[13];
    const float* b2    = (const float*)d_in[14];

    float* x = (float*)d_out;  // fp32 activation master lives in d_out

    char* ws = (char*)d_ws;
    size_t ofs = 0;
    int*   pos   = (int*)ws;                 ofs += 65536;
    float* tmp   = (float*)(ws + ofs);       ofs += (size_t)ROWS * DMODEL * 4;
    short* xb    = (short*)(ws + ofs);       ofs += (size_t)ROWS * DMODEL * 2;
    short* qkvb  = (short*)(ws + ofs);
    short* hb    = (short*)(ws + ofs);       // aliases qkvb..obuf (disjoint lifetime)
    ofs += (size_t)ROWS * 3 * DMODEL * 2;
    short* obuf  = (short*)(ws + ofs);       ofs += (size_t)ROWS * DMODEL * 2;
    short* WqkvT = (short*)(ws + ofs);       ofs += (size_t)LAYERS * DMODEL * 3 * DMODEL * 2;
    short* WfcT  = (short*)(ws + ofs);       ofs += (size_t)LAYERS * DMODEL * DMODEL * 2;
    short* W1T   = (short*)(ws + ofs);       ofs += (size_t)LAYERS * DMODEL * FFDIM * 2;
    short* W2T   = (short*)(ws + ofs);       ofs += (size_t)LAYERS * FFDIM * DMODEL * 2;

    wtrans_kernel<<<dim3(3 * DMODEL / 32, DMODEL / 32, LAYERS), dim3(32, 8), 0, stream>>>(
        Wqkv, WqkvT, DMODEL, 3 * DMODEL);
    wtrans_kernel<<<dim3(DMODEL / 32, DMODEL / 32, LAYERS), dim3(32, 8), 0, stream>>>(
        Wfc, WfcT, DMODEL, DMODEL);
    wtrans_kernel<<<dim3(FFDIM / 32, DMODEL / 32, LAYERS), dim3(32, 8), 0, stream>>>(
        W1, W1T, DMODEL, FFDIM);
    wtrans_kernel<<<dim3(DMODEL / 32, FFDIM / 32, LAYERS), dim3(32, 8), 0, stream>>>(
        W2, W2T, FFDIM, DMODEL);

    pos_scan_kernel<<<BATCH, SEQ, 0, stream>>>(mask, pos);
    add_pos_kernel<<<ROWS, 128, 0, stream>>>(x_in, pos, x, xb);

    for (int l = 0; l < LAYERS; ++l) {
        const short* wqkvT_l = WqkvT + (size_t)l * DMODEL * 3 * DMODEL;
        const short* wfcT_l  = WfcT + (size_t)l * DMODEL * DMODEL;
        const short* w1T_l   = W1T + (size_t)l * DMODEL * FFDIM;
        const short* w2T_l   = W2T + (size_t)l * FFDIM * DMODEL;
        const float* bfc_l   = bfc + (size_t)l * DMODEL;
        const float* b1_l    = b1 + (size_t)l * FFDIM;
        const float* b2_l    = b2 + (size_t)l * DMODEL;

        // qkv = x @ Wqkv  (bf16 out), N=1536: 768 blocks
        gemm_bf16_kernel<true, false, false><<<dim3(3 * DMODEL / 128, ROWS / 128), 256, 0, stream>>>(
            xb, wqkvT_l, nullptr, qkvb, ROWS, 3 * DMODEL, DMODEL);
        attn_mfma_kernel<<<dim3(SEQ / QTILE, BATCH * NHEAD), 512, 0, stream>>>(qkvb, mask, obuf);
        // tmp = obuf @ Wfc + bfc  (fp32 out), N=512: m64 tile -> 512 blocks
        gemm_bf16_m64_kernel<false, true, false><<<dim3(DMODEL / 128, ROWS / 64), 256, 0, stream>>>(
            obuf, wfcT_l, bfc_l, tmp, ROWS, DMODEL, DMODEL);
        ln_kernel<<<ROWS, 64, 0, stream>>>(tmp, x, xb, ln1_g + (size_t)l * DMODEL,
                                           ln1_b + (size_t)l * DMODEL);
        // h = relu(x @ W1 + b1)  (bf16 out), N=2048: 1024 blocks
        gemm_bf16_kernel<true, true, true><<<dim3(FFDIM / 128, ROWS / 128), 256, 0, stream>>>(
            xb, w1T_l, b1_l, hb, ROWS, FFDIM, DMODEL);
        // tmp = h @ W2 + b2  (fp32 out), N=512: m64 tile -> 512 blocks
        gemm_bf16_m64_kernel<false, true, false><<<dim3(DMODEL / 128, ROWS / 64), 256, 0, stream>>>(
            hb, w2T_l, b2_l, tmp, ROWS, DMODEL, FFDIM);
        ln_kernel<<<ROWS, 64, 0, stream>>>(tmp, x, xb, ln2_g + (size_t)l * DMODEL,
                                           ln2_b + (size_t)l * DMODEL);
    }
}

// Round 2
// 1091.441 us; speedup vs baseline: 1.0151x; 1.0040x over previous
//
#include <hip/hip_runtime.h>
#include <math.h>

// Problem constants
#define LAYERS 6
#define DMODEL 512
#define NHEAD 8
#define DHEAD 64
#define FFDIM 2048
#define BATCH 8
#define SEQ 1024
#define ROWS (BATCH * SEQ)   // 8192
#define EPS 1e-5f

typedef __attribute__((ext_vector_type(8))) short bf16x8;
typedef __attribute__((ext_vector_type(4))) float f32x4;
typedef __attribute__((ext_vector_type(16))) float f32x16;

__device__ inline short f2bf(float f) {
    union { float f; unsigned u; } v; v.f = f;
    unsigned r = (v.u + 0x7FFFu + ((v.u >> 16) & 1u)) >> 16;
    return (short)r;
}

// async global(bf16,16B) -> LDS staging; data lands at wave-uniform base + lane*16
#define GLOAD_LDS16(g, l)                                                      \
    __builtin_amdgcn_global_load_lds(                                          \
        (__attribute__((address_space(1))) void*)(g),                          \
        (__attribute__((address_space(3))) void*)(l), 16, 0, 0)

// ---------------------------------------------------------------------------
// Weight transpose + fp32->bf16: src [L][K][N] f32 -> dst [L][N][K] bf16
// ---------------------------------------------------------------------------
__global__ void wtrans_kernel(const float* __restrict__ src, short* __restrict__ dst,
                              int K, int N) {
    __shared__ float t[32][33];
    const size_t mofs = (size_t)blockIdx.z * K * N;
    src += mofs; dst += mofs;
    int n0 = blockIdx.x * 32, k0 = blockIdx.y * 32;
    int tx = threadIdx.x, ty = threadIdx.y;
#pragma unroll
    for (int i = 0; i < 4; ++i)
        t[ty + 8 * i][tx] = src[(size_t)(k0 + ty + 8 * i) * N + n0 + tx];
    __syncthreads();
#pragma unroll
    for (int i = 0; i < 4; ++i)
        dst[(size_t)(n0 + ty + 8 * i) * K + k0 + tx] = f2bf(t[tx][ty + 8 * i]);
}

// ---------------------------------------------------------------------------
// Positional scan
// ---------------------------------------------------------------------------
__global__ void pos_scan_kernel(const int* __restrict__ mask, int* __restrict__ pos) {
    __shared__ int sm[SEQ];
    int b = blockIdx.x;
    int t = threadIdx.x;
    int v = (mask[b * SEQ + t] != 0) ? 1 : 0;
    sm[t] = v;
    __syncthreads();
    for (int off = 1; off < SEQ; off <<= 1) {
        int add = (t >= off) ? sm[t - off] : 0;
        __syncthreads();
        sm[t] += add;
        __syncthreads();
    }
    pos[b * SEQ + t] = sm[t] * v;
}

// ---------------------------------------------------------------------------
// x = x_in + sin_pos_table[pos]; writes fp32 master + bf16 copy
// ---------------------------------------------------------------------------
__global__ void add_pos_kernel(const float* __restrict__ xin, const int* __restrict__ pos,
                               float* __restrict__ xout, short* __restrict__ xb) {
    int bs = blockIdx.x;
    int t = threadIdx.x;
    int p = pos[bs];
    int d0 = t * 4;
    const float C = -logf(10000.0f) * (1.0f / 255.0f);  // half-1 = 255
    float4 xv = *(const float4*)(xin + (size_t)bs * DMODEL + d0);
    float e[4];
#pragma unroll
    for (int j = 0; j < 4; ++j) {
        int d = d0 + j;
        if (p == 0) {
            e[j] = 0.0f;
        } else {
            int dd = (d < 256) ? d : d - 256;
            float freq = expf((float)dd * C);
            float ang = (float)p * freq;
            e[j] = (d < 256) ? sinf(ang) : cosf(ang);
        }
    }
    float4 ov;
    ov.x = xv.x + e[0]; ov.y = xv.y + e[1]; ov.z = xv.z + e[2]; ov.w = xv.w + e[3];
    *(float4*)(xout + (size_t)bs * DMODEL + d0) = ov;
    short4 sb;
    sb.x = f2bf(ov.x); sb.y = f2bf(ov.y); sb.z = f2bf(ov.z); sb.w = f2bf(ov.w);
    *(short4*)(xb + (size_t)bs * DMODEL + d0) = sb;
}

// ===========================================================================
// LDS k-granule swizzle (both GEMM kernels):
//   store: staging lane (r=lane>>2, pos=lane&3) fetches global granule
//          g' = (pos - (r>>1)) & 3  -> granule q of row m lands at LDS
//          position (q + ((m&15)>>1)) & 3.
//   read:  fragment (m, quad) at granule position (quad + (lr>>1)) & 3
//          (since m&15 == lr for all fragment rows).
//   Result: read bank-group (lr&1)*4 + (quad+(lr>>1))&3 covers all 8 groups
//   2-way across 16 lanes -> conflict-free (was 8-way).
// ===========================================================================

// ---------------------------------------------------------------------------
// bf16 MFMA GEMM, 128x128 tile, BK=32, 256 thr, single-barrier double-buffer.
// C[M,N] = A[M,K] @ BT[N,K]^T (+bias)(+relu).
// ---------------------------------------------------------------------------
template <bool OUTBF16, bool BIAS, bool RELU>
__global__ __launch_bounds__(256) void gemm_bf16_kernel(const short* __restrict__ A,
                                                        const short* __restrict__ BT,
                                                        const float* __restrict__ bias,
                                                        void* __restrict__ Cv,
                                                        int M, int N, int K) {
    __shared__ __attribute__((aligned(16))) short Asm[2][128 * 32];
    __shared__ __attribute__((aligned(16))) short Bsm[2][128 * 32];
    const int tid = threadIdx.x;
    const int w = tid >> 6;
    const int lane = tid & 63;
    const int quad = lane >> 4;
    const int lr = lane & 15;
    const int m0 = blockIdx.y * 128;
    const int n0 = blockIdx.x * 128;
    const int wm = (w >> 1) * 64;
    const int wn = (w & 1) * 64;

    // staging: 8 segments of 16 rows; wave w owns segs {2w, 2w+1}
    const int segr = lane >> 2;
    const int segk = (((lane & 3) - (lane >> 3)) & 3) * 8;  // swizzled source granule
    const int sA0 = w * 2, sA1 = w * 2 + 1;
    const short* gA0 = A + (size_t)(m0 + sA0 * 16 + segr) * K + segk;
    const short* gA1 = A + (size_t)(m0 + sA1 * 16 + segr) * K + segk;
    const short* gB0 = BT + (size_t)(n0 + sA0 * 16 + segr) * K + segk;
    const short* gB1 = BT + (size_t)(n0 + sA1 * 16 + segr) * K + segk;
    const int lofs0 = sA0 * 512 + lane * 8;
    const int lofs1 = sA1 * 512 + lane * 8;
    const int gp = ((quad + (lr >> 1)) & 3) * 8;            // swizzled read position

    f32x4 acc[4][4];
#pragma unroll
    for (int i = 0; i < 4; ++i)
#pragma unroll
        for (int j = 0; j < 4; ++j) { acc[i][j][0] = 0.f; acc[i][j][1] = 0.f; acc[i][j][2] = 0.f; acc[i][j][3] = 0.f; }

    GLOAD_LDS16(gA0, &Asm[0][lofs0]);
    GLOAD_LDS16(gA1, &Asm[0][lofs1]);
    GLOAD_LDS16(gB0, &Bsm[0][lofs0]);
    GLOAD_LDS16(gB1, &Bsm[0][lofs1]);

    const int nk = K >> 5;
    for (int i = 0; i < nk; ++i) {
        __syncthreads();
        if (i + 1 < nk) {
            const int k1 = (i + 1) * 32;
            const int nb = (i + 1) & 1;
            GLOAD_LDS16(gA0 + k1, &Asm[nb][lofs0]);
            GLOAD_LDS16(gA1 + k1, &Asm[nb][lofs1]);
            GLOAD_LDS16(gB0 + k1, &Bsm[nb][lofs0]);
            GLOAD_LDS16(gB1 + k1, &Bsm[nb][lofs1]);
        }
        const int cur = i & 1;
        bf16x8 af[4], bfr[4];
#pragma unroll
        for (int mt = 0; mt < 4; ++mt)
            af[mt] = *(const bf16x8*)&Asm[cur][(wm + mt * 16 + lr) * 32 + gp];
#pragma unroll
        for (int nt = 0; nt < 4; ++nt)
            bfr[nt] = *(const bf16x8*)&Bsm[cur][(wn + nt * 16 + lr) * 32 + gp];
#pragma unroll
        for (int mt = 0; mt < 4; ++mt)
#pragma unroll
            for (int nt = 0; nt < 4; ++nt)
                acc[mt][nt] = __builtin_amdgcn_mfma_f32_16x16x32_bf16(af[mt], bfr[nt], acc[mt][nt], 0, 0, 0);
    }

    float bv[4];
    if (BIAS) {
#pragma unroll
        for (int nt = 0; nt < 4; ++nt) bv[nt] = bias[n0 + wn + nt * 16 + lr];
    }
#pragma unroll
    for (int mt = 0; mt < 4; ++mt)
#pragma unroll
        for (int nt = 0; nt < 4; ++nt)
#pragma unroll
            for (int r = 0; r < 4; ++r) {
                float v = acc[mt][nt][r];
                if (BIAS) v += bv[nt];
                if (RELU) v = fmaxf(v, 0.f);
                int row = m0 + wm + mt * 16 + quad * 4 + r;
                int col = n0 + wn + nt * 16 + lr;
                if (OUTBF16)
                    ((short*)Cv)[(size_t)row * N + col] = f2bf(v);
                else
                    ((float*)Cv)[(size_t)row * N + col] = v;
            }
}

// ---------------------------------------------------------------------------
// bf16 MFMA GEMM, 64x128 tile (for N=512 GEMMs: 512 blocks = 2/CU, A streamed
// exactly once, B fits per-XCD L2). BK=32, 256 thr = 4 waves (2x2 of 32x64).
// ---------------------------------------------------------------------------
template <bool OUTBF16, bool BIAS, bool RELU>
__global__ __launch_bounds__(256) void gemm_bf16_m64_kernel(const short* __restrict__ A,
                                                            const short* __restrict__ BT,
                                                            const float* __restrict__ bias,
                                                            void* __restrict__ Cv,
                                                            int M, int N, int K) {
    __shared__ __attribute__((aligned(16))) short Asm[2][64 * 32];
    __shared__ __attribute__((aligned(16))) short Bsm[2][128 * 32];
    const int tid = threadIdx.x;
    const int w = tid >> 6;
    const int lane = tid & 63;
    const int quad = lane >> 4;
    const int lr = lane & 15;
    const int m0 = blockIdx.y * 64;
    const int n0 = blockIdx.x * 128;
    const int wm = (w >> 1) * 32;
    const int wn = (w & 1) * 64;

    // staging: A = 4 segs (wave w -> seg w), B = 8 segs (wave w -> 2w, 2w+1)
    const int segr = lane >> 2;
    const int segk = (((lane & 3) - (lane >> 3)) & 3) * 8;  // swizzled source granule
    const short* gA  = A + (size_t)(m0 + w * 16 + segr) * K + segk;
    const short* gB0 = BT + (size_t)(n0 + (2 * w) * 16 + segr) * K + segk;
    const short* gB1 = BT + (size_t)(n0 + (2 * w + 1) * 16 + segr) * K + segk;
    const int lA  = w * 512 + lane * 8;
    const int lB0 = (2 * w) * 512 + lane * 8;
    const int lB1 = (2 * w + 1) * 512 + lane * 8;
    const int gp = ((quad + (lr >> 1)) & 3) * 8;            // swizzled read position

    f32x4 acc[2][4];
#pragma unroll
    for (int i = 0; i < 2; ++i)
#pragma unroll
        for (int j = 0; j < 4; ++j) { acc[i][j][0] = 0.f; acc[i][j][1] = 0.f; acc[i][j][2] = 0.f; acc[i][j][3] = 0.f; }

    GLOAD_LDS16(gA, &Asm[0][lA]);
    GLOAD_LDS16(gB0, &Bsm[0][lB0]);
    GLOAD_LDS16(gB1, &Bsm[0][lB1]);

    const int nk = K >> 5;
    for (int i = 0; i < nk; ++i) {
        __syncthreads();
        if (i + 1 < nk) {
            const int k1 = (i + 1) * 32;
            const int nb = (i + 1) & 1;
            GLOAD_LDS16(gA + k1, &Asm[nb][lA]);
            GLOAD_LDS16(gB0 + k1, &Bsm[nb][lB0]);
            GLOAD_LDS16(gB1 + k1, &Bsm[nb][lB1]);
        }
        const int cur = i & 1;
        bf16x8 af[2], bfr[4];
#pragma unroll
        for (int mt = 0; mt < 2; ++mt)
            af[mt] = *(const bf16x8*)&Asm[cur][(wm + mt * 16 + lr) * 32 + gp];
#pragma unroll
        for (int nt = 0; nt < 4; ++nt)
            bfr[nt] = *(const bf16x8*)&Bsm[cur][(wn + nt * 16 + lr) * 32 + gp];
#pragma unroll
        for (int mt = 0; mt < 2; ++mt)
#pragma unroll
            for (int nt = 0; nt < 4; ++nt)
                acc[mt][nt] = __builtin_amdgcn_mfma_f32_16x16x32_bf16(af[mt], bfr[nt], acc[mt][nt], 0, 0, 0);
    }

    float bv[4];
    if (BIAS) {
#pragma unroll
        for (int nt = 0; nt < 4; ++nt) bv[nt] = bias[n0 + wn + nt * 16 + lr];
    }
#pragma unroll
    for (int mt = 0; mt < 2; ++mt)
#pragma unroll
        for (int nt = 0; nt < 4; ++nt)
#pragma unroll
            for (int r = 0; r < 4; ++r) {
                float v = acc[mt][nt][r];
                if (BIAS) v += bv[nt];
                if (RELU) v = fmaxf(v, 0.f);
                int row = m0 + wm + mt * 16 + quad * 4 + r;
                int col = n0 + wn + nt * 16 + lr;
                if (OUTBF16)
                    ((short*)Cv)[(size_t)row * N + col] = f2bf(v);
                else
                    ((float*)Cv)[(size_t)row * N + col] = v;
            }
}

// ---------------------------------------------------------------------------
// bf16-MFMA flash attention v4: 32x32x16 MFMA shape. QTILE=256, 512 thr =
// 8 waves x 32 q-rows. Swapped QK^T (S^T = mfma(K, Q)) leaves P^T[key][q]
// in registers; the PV A-fragment is built fully IN-REGISTER via
// cvt_pk_bf16 + cross-half shfl_xor(32) + select (no P LDS round-trip).
// 32x32 shape gives 2x flops per LDS fragment byte vs 16x16 (kf/vf reads
// per q-row halve). No-rescale softmax (fixed shift 8, exact after
// normalization), double-buffered K/V staging, ONE barrier per tile.
//
// Layouts (mfma_f32_32x32x16_bf16):
//   A:  row = lane&31, k = (lane>>5)*8 + j   (4 VGPR = 8 bf16)
//   B:  col = lane&31, k = (lane>>5)*8 + j
//   C:  col = lane&31, row = (reg&3) + 8*(reg>>2) + 4*(lane>>5)
// QK^T: A=K rows (key), B=Q^T -> lane holds P^T[key(reg,hi)][q=lane&31].
// PV:   A=P rows (q=lane&31, k=key), B=V^T (k=key, col=d).
// Key bit2 of a P value maps to the holding lane-half -> PV A-frag words
// {j<4} come from lo-half lanes, {j>=4} from hi-half lanes (one exchange).
// ---------------------------------------------------------------------------
#define QTILE 256
__global__ __launch_bounds__(512, 2) void attn_mfma_kernel(const short* __restrict__ qkv,
                                                           const int* __restrict__ mask,
                                                           short* __restrict__ o) {
    __shared__ __attribute__((aligned(16))) short Ks[2][64][72];    // [key][d]
    __shared__ __attribute__((aligned(16))) short Vt[2][64][72];    // [d][key]
    __shared__ __attribute__((aligned(16))) float Msf[2][64];

    const int qt = blockIdx.x;          // 0..3
    const int bh = blockIdx.y;          // 0..63
    const int b = bh >> 3, h = bh & 7;
    const int tid = threadIdx.x;
    const int w = tid >> 6;             // wave 0..7
    const int lane = tid & 63;
    const int c31 = lane & 31;
    const int hi = lane >> 5;
    const size_t seqrow = (size_t)b * SEQ;

    // Q as B-operand: lane holds Q^T[k=d=16ks+8hi+j][q=c31]
    bf16x8 qf[4];
#pragma unroll
    for (int ks = 0; ks < 4; ++ks)
        qf[ks] = *(const bf16x8*)(qkv +
            (seqrow + qt * QTILE + w * 32 + c31) * (3 * DMODEL)
            + h * DHEAD + ks * 16 + hi * 8);

    const bool isK = (tid < 256);
    const int st = isK ? tid : tid - 256;
    const int kkey = st >> 2;
    const int kg = (st & 3) * 8;
    const int vkp = st & 31;
    const int vdg = st >> 5;
    const short* gK = qkv + (seqrow + kkey) * (3 * DMODEL) + DMODEL + h * DHEAD + kg;
    const short* gV = qkv + (seqrow + 2 * vkp) * (3 * DMODEL) + 2 * DMODEL + h * DHEAD + vdg * 8;

    bf16x8 r0, r1;
    int mreg = 0;

    {
        if (isK) {
            r0 = *(const bf16x8*)(gK);
            r1 = *(const bf16x8*)(gK + 32);
        } else {
            r0 = *(const bf16x8*)(gV);
            r1 = *(const bf16x8*)(gV + 3 * DMODEL);
        }
        if (tid < 64) mreg = mask[seqrow + tid];
        if (isK) {
            *(bf16x8*)&Ks[0][kkey][kg] = r0;
            *(bf16x8*)&Ks[0][kkey][kg + 32] = r1;
        } else {
#pragma unroll
            for (int i = 0; i < 8; ++i) {
                short2 p; p.x = r0[i]; p.y = r1[i];
                *(short2*)&Vt[0][vdg * 8 + i][vkp * 2] = p;
            }
        }
        if (tid < 64) Msf[0][tid] = mreg ? 1.0f : 0.0f;
    }
    __syncthreads();

    f32x16 O0, O1;
    float rs = 0.f;
#pragma unroll
    for (int i = 0; i < 16; ++i) { O0[i] = 0.f; O1[i] = 0.f; }

    for (int kt = 0; kt < 16; ++kt) {
        const int cur = kt & 1;
        {
            const size_t ofs = (size_t)((kt + 1) & 15) * 64 * (3 * DMODEL);
            if (isK) {
                r0 = *(const bf16x8*)(gK + ofs);
                r1 = *(const bf16x8*)(gK + ofs + 32);
            } else {
                r0 = *(const bf16x8*)(gV + ofs);
                r1 = *(const bf16x8*)(gV + ofs + 3 * DMODEL);
            }
            if (tid < 64) mreg = mask[seqrow + ((kt + 1) & 15) * 64 + tid];
        }

        // QK^T: S^T[key][q], two 32-key tiles
        f32x16 S0, S1;
#pragma unroll
        for (int i = 0; i < 16; ++i) { S0[i] = 0.f; S1[i] = 0.f; }
#pragma unroll
        for (int ks = 0; ks < 4; ++ks) {
            bf16x8 k0 = *(const bf16x8*)&Ks[cur][c31][ks * 16 + hi * 8];
            bf16x8 k1 = *(const bf16x8*)&Ks[cur][32 + c31][ks * 16 + hi * 8];
            S0 = __builtin_amdgcn_mfma_f32_32x32x16_bf16(k0, qf[ks], S0, 0, 0, 0);
            S1 = __builtin_amdgcn_mfma_f32_32x32x16_bf16(k1, qf[ks], S1, 0, 0, 0);
        }

        // softmax (no rescale, shift 8) + pack to bf16 pairs.
        // S reg r holds key = (r&3) + 8*(r>>2) + 4*hi (+32 for S1).
        unsigned pkd[2][8];
#pragma unroll
        for (int g = 0; g < 4; ++g) {
            f32x4 m0 = *(const f32x4*)&Msf[cur][g * 8 + hi * 4];
            f32x4 m1 = *(const f32x4*)&Msf[cur][32 + g * 8 + hi * 4];
            float p0[4], p1[4];
#pragma unroll
            for (int j = 0; j < 4; ++j) {
                p0[j] = __expf(S0[g * 4 + j] - 8.0f) * m0[j];
                p1[j] = __expf(S1[g * 4 + j] - 8.0f) * m1[j];
                rs += p0[j] + p1[j];
            }
            asm("v_cvt_pk_bf16_f32 %0, %1, %2" : "=v"(pkd[0][g * 2])     : "v"(p0[0]), "v"(p0[1]));
            asm("v_cvt_pk_bf16_f32 %0, %1, %2" : "=v"(pkd[0][g * 2 + 1]) : "v"(p0[2]), "v"(p0[3]));
            asm("v_cvt_pk_bf16_f32 %0, %1, %2" : "=v"(pkd[1][g * 2])     : "v"(p1[0]), "v"(p1[1]));
            asm("v_cvt_pk_bf16_f32 %0, %1, %2" : "=v"(pkd[1][g * 2 + 1]) : "v"(p1[2]), "v"(p1[3]));
        }

        // PV: build A-frag per ks in-register.
        // frag(ks) dwords: d0,d1 = keys 16ks+8hi+{0..3} (held by lo lanes at
        // idx i0 = (ks&1)*4 for lo consumers, i0+2 for hi consumers);
        // d2,d3 = keys +{4..7} (held by hi lanes at the same indices).
#pragma unroll
        for (int ks = 0; ks < 4; ++ks) {
            const int k2 = ks >> 1;
            const int i0 = (ks & 1) * 4;
            unsigned c0a = pkd[k2][i0 + 0], c0b = pkd[k2][i0 + 1];
            unsigned c1a = pkd[k2][i0 + 2], c1b = pkd[k2][i0 + 3];
            unsigned x1a = (unsigned)__shfl_xor((int)c1a, 32);
            unsigned x1b = (unsigned)__shfl_xor((int)c1b, 32);
            unsigned x0a = (unsigned)__shfl_xor((int)c0a, 32);
            unsigned x0b = (unsigned)__shfl_xor((int)c0b, 32);
            union { unsigned u[4]; bf16x8 v; } pb;
            pb.u[0] = hi ? x1a : c0a;   // d0: lo->own C0 ; hi->partner C1
            pb.u[1] = hi ? x1b : c0b;   // d1
            pb.u[2] = hi ? c1a : x0a;   // d2: lo->partner C0 ; hi->own C1
            pb.u[3] = hi ? c1b : x0b;   // d3
            bf16x8 v0 = *(const bf16x8*)&Vt[cur][c31][ks * 16 + hi * 8];
            bf16x8 v1 = *(const bf16x8*)&Vt[cur][32 + c31][ks * 16 + hi * 8];
            O0 = __builtin_amdgcn_mfma_f32_32x32x16_bf16(pb.v, v0, O0, 0, 0, 0);
            O1 = __builtin_amdgcn_mfma_f32_32x32x16_bf16(pb.v, v1, O1, 0, 0, 0);
        }

        {
            const int nb = cur ^ 1;
            if (isK) {
                *(bf16x8*)&Ks[nb][kkey][kg] = r0;
                *(bf16x8*)&Ks[nb][kkey][kg + 32] = r1;
            } else {
#pragma unroll
                for (int i = 0; i < 8; ++i) {
                    short2 p; p.x = r0[i]; p.y = r1[i];
                    *(short2*)&Vt[nb][vdg * 8 + i][vkp * 2] = p;
                }
            }
            if (tid < 64) Msf[nb][tid] = mreg ? 1.0f : 0.0f;
        }
        __syncthreads();
    }

    // rs: lane holds partial denominator for q=c31 over its own-half keys.
    rs += __shfl_xor(rs, 32);   // full denominator for q=c31, all lanes

#pragma unroll
    for (int r = 0; r < 16; ++r) {
        const int qr = (r & 3) + 8 * (r >> 2) + 4 * hi;   // O row = q
        const float inv = 1.0f / __shfl(rs, qr);
        const int row = qt * QTILE + w * 32 + qr;
        o[(seqrow + row) * DMODEL + h * DHEAD + c31]      = f2bf(O0[r] * inv);
        o[(seqrow + row) * DMODEL + h * DHEAD + 32 + c31] = f2bf(O1[r] * inv);
    }
}

// ---------------------------------------------------------------------------
// x = LayerNorm(tmp + x) * g + b; writes fp32 master (in-place) + bf16 copy
// ---------------------------------------------------------------------------
__global__ __launch_bounds__(64) void ln_kernel(const float* __restrict__ tmp,
                                                float* __restrict__ x,
                                                short* __restrict__ xb,
                                                const float* __restrict__ g,
                                                const float* __restrict__ bta) {
    const int row = blockIdx.x;
    const int t = threadIdx.x;
    const size_t base = (size_t)row * DMODEL + t * 8;
    float4 x0 = *(const float4*)(x + base);
    float4 x1 = *(const float4*)(x + base + 4);
    float4 t0 = *(const float4*)(tmp + base);
    float4 t1 = *(const float4*)(tmp + base + 4);
    float v[8];
    v[0] = x0.x + t0.x; v[1] = x0.y + t0.y; v[2] = x0.z + t0.z; v[3] = x0.w + t0.w;
    v[4] = x1.x + t1.x; v[5] = x1.y + t1.y; v[6] = x1.z + t1.z; v[7] = x1.w + t1.w;
    float s = 0.f, sq = 0.f;
#pragma unroll
    for (int i = 0; i < 8; ++i) { s += v[i]; sq += v[i] * v[i]; }
#pragma unroll
    for (int off = 1; off < 64; off <<= 1) {
        s += __shfl_xor(s, off);
        sq += __shfl_xor(sq, off);
    }
    float mu = s * (1.0f / DMODEL);
    float var = sq * (1.0f / DMODEL) - mu * mu;
    float r = rsqrtf(var + EPS);
    float4 g0 = *(const float4*)(g + t * 8);
    float4 g1 = *(const float4*)(g + t * 8 + 4);
    float4 b0 = *(const float4*)(bta + t * 8);
    float4 b1 = *(const float4*)(bta + t * 8 + 4);
    float ov[8];
    ov[0] = (v[0] - mu) * r * g0.x + b0.x;
    ov[1] = (v[1] - mu) * r * g0.y + b0.y;
    ov[2] = (v[2] - mu) * r * g0.z + b0.z;
    ov[3] = (v[3] - mu) * r * g0.w + b0.w;
    ov[4] = (v[4] - mu) * r * g1.x + b1.x;
    ov[5] = (v[5] - mu) * r * g1.y + b1.y;
    ov[6] = (v[6] - mu) * r * g1.z + b1.z;
    ov[7] = (v[7] - mu) * r * g1.w + b1.w;
    *(float4*)(x + base) = *(float4*)&ov[0];
    *(float4*)(x + base + 4) = *(float4*)&ov[4];
    bf16x8 ob;
#pragma unroll
    for (int i = 0; i < 8; ++i) ob[i] = f2bf(ov[i]);
    *(bf16x8*)(xb + base) = ob;
}

// ---------------------------------------------------------------------------
extern "C" void kernel_launch(void* const* d_in, const int* in_sizes, int n_in,
                              void* d_out, int out_size, void* d_ws, size_t ws_size,
                              hipStream_t stream) {
    const float* x_in  = (const float*)d_in[0];
    const int*   mask  = (const int*)d_in[3];
    const float* Wqkv  = (const float*)d_in[4];
    const float* Wfc   = (const float*)d_in[5];
    const float* bfc   = (const float*)d_in[6];
    const float* ln1_g = (const float*)d_in[7];
    const float* ln1_b = (const float*)d_in[8];
    const float* ln2_g = (const float*)d_in[9];
    const float* ln2_b = (const float*)d_in[10];
    const float* W1    = (const float*)d_in[11];
    const float* b1    = (const float*)d_in[12];
    const float* W2    = (const float*)d_in[13];
    const float* b2    = (const float*)d_in[14];

    float* x = (float*)d_out;  // fp32 activation master lives in d_out

    char* ws = (char*)d_ws;
    size_t ofs = 0;
    int*   pos   = (int*)ws;                 ofs += 65536;
    float* tmp   = (float*)(ws + ofs);       ofs += (size_t)ROWS * DMODEL * 4;
    short* xb    = (short*)(ws + ofs);       ofs += (size_t)ROWS * DMODEL * 2;
    short* qkvb  = (short*)(ws + ofs);
    short* hb    = (short*)(ws + ofs);       // aliases qkvb..obuf (disjoint lifetime)
    ofs += (size_t)ROWS * 3 * DMODEL * 2;
    short* obuf  = (short*)(ws + ofs);       ofs += (size_t)ROWS * DMODEL * 2;
    short* WqkvT = (short*)(ws + ofs);       ofs += (size_t)LAYERS * DMODEL * 3 * DMODEL * 2;
    short* WfcT  = (short*)(ws + ofs);       ofs += (size_t)LAYERS * DMODEL * DMODEL * 2;
    short* W1T   = (short*)(ws + ofs);       ofs += (size_t)LAYERS * DMODEL * FFDIM * 2;
    short* W2T   = (short*)(ws + ofs);       ofs += (size_t)LAYERS * FFDIM * DMODEL * 2;

    wtrans_kernel<<<dim3(3 * DMODEL / 32, DMODEL / 32, LAYERS), dim3(32, 8), 0, stream>>>(
        Wqkv, WqkvT, DMODEL, 3 * DMODEL);
    wtrans_kernel<<<dim3(DMODEL / 32, DMODEL / 32, LAYERS), dim3(32, 8), 0, stream>>>(
        Wfc, WfcT, DMODEL, DMODEL);
    wtrans_kernel<<<dim3(FFDIM / 32, DMODEL / 32, LAYERS), dim3(32, 8), 0, stream>>>(
        W1, W1T, DMODEL, FFDIM);
    wtrans_kernel<<<dim3(DMODEL / 32, FFDIM / 32, LAYERS), dim3(32, 8), 0, stream>>>(
        W2, W2T, FFDIM, DMODEL);

    pos_scan_kernel<<<BATCH, SEQ, 0, stream>>>(mask, pos);
    add_pos_kernel<<<ROWS, 128, 0, stream>>>(x_in, pos, x, xb);

    for (int l = 0; l < LAYERS; ++l) {
        const short* wqkvT_l = WqkvT + (size_t)l * DMODEL * 3 * DMODEL;
        const short* wfcT_l  = WfcT + (size_t)l * DMODEL * DMODEL;
        const short* w1T_l   = W1T + (size_t)l * DMODEL * FFDIM;
        const short* w2T_l   = W2T + (size_t)l * FFDIM * DMODEL;
        const float* bfc_l   = bfc + (size_t)l * DMODEL;
        const float* b1_l    = b1 + (size_t)l * FFDIM;
        const float* b2_l    = b2 + (size_t)l * DMODEL;

        // qkv = x @ Wqkv  (bf16 out), N=1536: 768 blocks
        gemm_bf16_kernel<true, false, false><<<dim3(3 * DMODEL / 128, ROWS / 128), 256, 0, stream>>>(
            xb, wqkvT_l, nullptr, qkvb, ROWS, 3 * DMODEL, DMODEL);
        attn_mfma_kernel<<<dim3(SEQ / QTILE, BATCH * NHEAD), 512, 0, stream>>>(qkvb, mask, obuf);
        // tmp = obuf @ Wfc + bfc  (fp32 out), N=512: m64 tile -> 512 blocks
        gemm_bf16_m64_kernel<false, true, false><<<dim3(DMODEL / 128, ROWS / 64), 256, 0, stream>>>(
            obuf, wfcT_l, bfc_l, tmp, ROWS, DMODEL, DMODEL);
        ln_kernel<<<ROWS, 64, 0, stream>>>(tmp, x, xb, ln1_g + (size_t)l * DMODEL,
                                           ln1_b + (size_t)l * DMODEL);
        // h = relu(x @ W1 + b1)  (bf16 out), N=2048: 1024 blocks
        gemm_bf16_kernel<true, true, true><<<dim3(FFDIM / 128, ROWS / 128), 256, 0, stream>>>(
            xb, w1T_l, b1_l, hb, ROWS, FFDIM, DMODEL);
        // tmp = h @ W2 + b2  (fp32 out), N=512: m64 tile -> 512 blocks
        gemm_bf16_m64_kernel<false, true, false><<<dim3(DMODEL / 128, ROWS / 64), 256, 0, stream>>>(
            hb, w2T_l, b2_l, tmp, ROWS, DMODEL, FFDIM);
        ln_kernel<<<ROWS, 64, 0, stream>>>(tmp, x, xb, ln2_g + (size_t)l * DMODEL,
                                           ln2_b + (size_t)l * DMODEL);
    }
}